// Round 1
// baseline (147.199 us; speedup 1.0000x reference)
//
#include <hip/hip_runtime.h>
#include <stdint.h>

#define AS1 __attribute__((address_space(1)))
#define AS3 __attribute__((address_space(3)))

typedef __attribute__((ext_vector_type(8))) short short8;
typedef __attribute__((ext_vector_type(4))) float f32x4;

// ---------- bf16 helpers (RNE) ----------
__device__ __forceinline__ short f2bf(float f) {
  union { float f; unsigned u; } v; v.f = f;
  unsigned r = v.u + 0x7fffu + ((v.u >> 16) & 1u);
  return (short)(r >> 16);
}
__device__ __forceinline__ float bf2f(short s) {
  union { unsigned u; float f; } v; v.u = ((unsigned)(unsigned short)s) << 16;
  return v.f;
}
__device__ __forceinline__ float bf_lo(unsigned w) { union { unsigned u; float f; } v; v.u = w << 16;          return v.f; }
__device__ __forceinline__ float bf_hi(unsigned w) { union { unsigned u; float f; } v; v.u = w & 0xffff0000u;  return v.f; }

// ---------- K1: W2t[j][d] = sum_e weight[d][e] * fcw[e][j], bf16 out (transposed for GEMM B) ----------
__global__ __launch_bounds__(1024) void k_w2t(const float* __restrict__ W,
                                              const float* __restrict__ F,
                                              short* __restrict__ W2t) {
  __shared__ float sW[32][33];  // [d_local][e_local]
  __shared__ float sF[32][33];  // [e_local][j_local]
  const int tx = threadIdx.x;   // d_local (coalesced store dim)
  const int ty = threadIdx.y;   // j_local
  const int d0 = blockIdx.x * 32, j0 = blockIdx.y * 32;
  float acc = 0.f;
  for (int e0 = 0; e0 < 512; e0 += 32) {
    sW[ty][tx] = W[(size_t)(d0 + ty) * 512 + e0 + tx];   // row=d, col=e (coalesced in e)
    sF[ty][tx] = F[(size_t)(e0 + ty) * 512 + j0 + tx];   // row=e, col=j (coalesced in j)
    __syncthreads();
#pragma unroll
    for (int e = 0; e < 32; ++e) acc += sW[tx][e] * sF[e][ty];
    __syncthreads();
  }
  W2t[(size_t)(j0 + ty) * 512 + d0 + tx] = f2bf(acc);
}

// ---------- K2: fp32 -> bf16 convert, 8 elems/thread ----------
__global__ __launch_bounds__(256) void k_f32_to_bf16(const float* __restrict__ in,
                                                     short* __restrict__ out, int n8) {
  int i = blockIdx.x * 256 + threadIdx.x;
  if (i >= n8) return;
  const float4* p = (const float4*)in;
  float4 a = p[i * 2], b = p[i * 2 + 1];
  short8 o;
  o[0] = f2bf(a.x); o[1] = f2bf(a.y); o[2] = f2bf(a.z); o[3] = f2bf(a.w);
  o[4] = f2bf(b.x); o[5] = f2bf(b.y); o[6] = f2bf(b.z); o[7] = f2bf(b.w);
  ((short8*)out)[i] = o;
}

// ---------- K3: h = A(bf16)[M,K] @ B, B given as Bt[N,K] (bf16). 128x128 tile, BK=64 ----------
#define BM 128
#define BN 128
#define BKG 64
__global__ __launch_bounds__(256) void k_gemm(const short* __restrict__ A,
                                              const short* __restrict__ Bt,
                                              short* __restrict__ C,
                                              int M, int Ncols, int K) {
  __shared__ __align__(16) short sA[BM * BKG];
  __shared__ __align__(16) short sB[BN * BKG];
  const int tid  = threadIdx.x;
  const int lane = tid & 63;
  const int wid  = tid >> 6;
  const int wm   = wid >> 1;   // 2x2 wave grid, each wave 64x64
  const int wn   = wid & 1;
  const int bn0  = blockIdx.x * BN;
  const int bm0  = blockIdx.y * BM;

  f32x4 acc[4][4] = {};

  // staging geometry: chunk c = r*256+tid -> row = r*32 + (tid>>3), slot = tid&7
  // LDS is linear in chunk order; global source is inverse-XOR-swizzled (rule 21)
  const int srow  = tid >> 3;                       // 0..31 (row base, +32 per round)
  const int sslot = (tid & 7) ^ (srow & 7);         // swizzled k-slot in global
  const int lslot = (tid & 7);                      // linear LDS slot

  for (int kt = 0; kt < K / BKG; ++kt) {
    const int kbase = kt * BKG;
#pragma unroll
    for (int r = 0; r < 4; ++r) {
      int row = r * 32 + srow;
      const short* gA = A + (size_t)(bm0 + row) * K + kbase + sslot * 8;
      short* lA = sA + row * BKG + lslot * 8;
      __builtin_amdgcn_global_load_lds((const AS1 void*)gA, (AS3 void*)lA, 16, 0, 0);
    }
#pragma unroll
    for (int r = 0; r < 4; ++r) {
      int row = r * 32 + srow;
      const short* gB = Bt + (size_t)(bn0 + row) * K + kbase + sslot * 8;
      short* lB = sB + row * BKG + lslot * 8;
      __builtin_amdgcn_global_load_lds((const AS1 void*)gB, (AS3 void*)lB, 16, 0, 0);
    }
    __syncthreads();
#pragma unroll
    for (int ks = 0; ks < 2; ++ks) {
      short8 af[4], bfr[4];
#pragma unroll
      for (int i = 0; i < 4; ++i) {
        int row  = wm * 64 + i * 16 + (lane & 15);
        int slot = (ks * 4 + (lane >> 4)) ^ (row & 7);
        af[i] = *(const short8*)(sA + row * BKG + slot * 8);
      }
#pragma unroll
      for (int j = 0; j < 4; ++j) {
        int row  = wn * 64 + j * 16 + (lane & 15);
        int slot = (ks * 4 + (lane >> 4)) ^ (row & 7);
        bfr[j] = *(const short8*)(sB + row * BKG + slot * 8);
      }
#pragma unroll
      for (int i = 0; i < 4; ++i)
#pragma unroll
        for (int j = 0; j < 4; ++j)
          acc[i][j] = __builtin_amdgcn_mfma_f32_16x16x32_bf16(af[i], bfr[j], acc[i][j], 0, 0, 0);
    }
    __syncthreads();
  }
  // epilogue: C/D layout col=lane&15, row=(lane>>4)*4+reg  [m89-verified]
  const int r4 = (lane >> 4) * 4;
  const int cc = lane & 15;
#pragma unroll
  for (int i = 0; i < 4; ++i)
#pragma unroll
    for (int j = 0; j < 4; ++j) {
      int gc = bn0 + wn * 64 + j * 16 + cc;
#pragma unroll
      for (int rg = 0; rg < 4; ++rg) {
        int gr = bm0 + wm * 64 + i * 16 + r4 + rg;
        C[(size_t)gr * Ncols + gc] = f2bf(acc[i][j][rg]);
      }
    }
}

// ---------- K4: el/er per node,head. one wave per node ----------
__global__ __launch_bounds__(256) void k_eler(const short* __restrict__ h,
                                              const float* __restrict__ al,
                                              const float* __restrict__ ar,
                                              float* __restrict__ el,
                                              float* __restrict__ er, int N) {
  int node = blockIdx.x * 4 + (threadIdx.x >> 6);
  if (node >= N) return;
  int lane = threadIdx.x & 63;
  int c0 = lane * 8;
  short8 hv = ((const short8*)(h + (size_t)node * 512))[lane];
  float pl = 0.f, pr = 0.f;
#pragma unroll
  for (int j = 0; j < 8; ++j) {
    float x = bf2f(hv[j]);
    pl += x * al[c0 + j];
    pr += x * ar[c0 + j];
  }
#pragma unroll
  for (int d = 1; d < 16; d <<= 1) {
    pl += __shfl_xor(pl, d);
    pr += __shfl_xor(pr, d);
  }
  if ((lane & 15) == 0) {
    el[node * 4 + (lane >> 4)] = pl;
    er[node * 4 + (lane >> 4)] = pr;
  }
}

// ---------- K5: CSR build ----------
__global__ __launch_bounds__(256) void k_hist(const int* __restrict__ dst, int* __restrict__ deg, int E) {
  int e = blockIdx.x * 256 + threadIdx.x;
  if (e < E) atomicAdd(&deg[dst[e]], 1);
}

__global__ __launch_bounds__(1024) void k_scan(const int* __restrict__ deg, int* __restrict__ off,
                                               int* __restrict__ cursor, int N) {
  __shared__ int lds[1024];
  int t = threadIdx.x;
  int base = t * 16;
  int loc[16];
  int s = 0;
#pragma unroll
  for (int j = 0; j < 16; ++j) { loc[j] = s; s += deg[base + j]; }
  lds[t] = s;
  __syncthreads();
  for (int d = 1; d < 1024; d <<= 1) {
    int v = (t >= d) ? lds[t - d] : 0;
    __syncthreads();
    lds[t] += v;
    __syncthreads();
  }
  int prefix = (t == 0) ? 0 : lds[t - 1];
#pragma unroll
  for (int j = 0; j < 16; ++j) {
    int o = prefix + loc[j];
    off[base + j] = o;
    cursor[base + j] = o;
  }
  if (t == 1023) off[N] = lds[1023];
}

__global__ __launch_bounds__(256) void k_scatter(const int* __restrict__ src, const int* __restrict__ dst,
                                                 int* __restrict__ cursor, int* __restrict__ csr, int E) {
  int e = blockIdx.x * 256 + threadIdx.x;
  if (e < E) {
    int p = atomicAdd(&cursor[dst[e]], 1);
    csr[p] = src[e];
  }
}

// ---------- K6: per-dst online-softmax aggregation. one wave per node ----------
__global__ __launch_bounds__(256) void k_aggregate(const int* __restrict__ off, const int* __restrict__ csr,
                                                   const float* __restrict__ el, const float* __restrict__ er,
                                                   const short* __restrict__ h, const float* __restrict__ bias,
                                                   float* __restrict__ out, int N) {
  int node = blockIdx.x * 4 + (threadIdx.x >> 6);
  if (node >= N) return;
  int lane = threadIdx.x & 63;
  int hh = lane >> 4;            // head for this lane's columns
  int c0 = lane * 8;             // output cols c0..c0+7
  float ern = er[node * 4 + hh];
  int p0 = off[node], p1 = off[node + 1];
  float m = -1e30f, ssum = 0.f;
  float acc[8];
#pragma unroll
  for (int j = 0; j < 8; ++j) acc[j] = 0.f;
  for (int p = p0; p < p1; ++p) {
    int sv = csr[p];
    float e = el[sv * 4 + hh] + ern;
    e = (e > 0.f) ? e : 0.2f * e;             // leaky_relu 0.2
    float mn = fmaxf(m, e);
    float scale = __expf(m - mn);             // m=-1e30 on first iter -> 0
    float pw = __expf(e - mn);
    ssum = ssum * scale + pw;
    uint4 hv = ((const uint4*)(h + (size_t)sv * 512))[lane];
    acc[0] = acc[0] * scale + pw * bf_lo(hv.x);
    acc[1] = acc[1] * scale + pw * bf_hi(hv.x);
    acc[2] = acc[2] * scale + pw * bf_lo(hv.y);
    acc[3] = acc[3] * scale + pw * bf_hi(hv.y);
    acc[4] = acc[4] * scale + pw * bf_lo(hv.z);
    acc[5] = acc[5] * scale + pw * bf_hi(hv.z);
    acc[6] = acc[6] * scale + pw * bf_lo(hv.w);
    acc[7] = acc[7] * scale + pw * bf_hi(hv.w);
    m = mn;
  }
  float inv = 1.f / ssum;   // every node has a self-loop -> ssum > 0
  float4 b0 = *(const float4*)(bias + c0);
  float4 b1 = *(const float4*)(bias + c0 + 4);
  float4 o0, o1;
  o0.x = acc[0] * inv + b0.x; o0.y = acc[1] * inv + b0.y;
  o0.z = acc[2] * inv + b0.z; o0.w = acc[3] * inv + b0.w;
  o1.x = acc[4] * inv + b1.x; o1.y = acc[5] * inv + b1.y;
  o1.z = acc[6] * inv + b1.z; o1.w = acc[7] * inv + b1.w;
  float* op = out + (size_t)node * 512 + c0;
  *(float4*)op = o0;
  *(float4*)(op + 4) = o1;
}

// ---------- launch ----------
extern "C" void kernel_launch(void* const* d_in, const int* in_sizes, int n_in,
                              void* d_out, int out_size, void* d_ws, size_t ws_size,
                              hipStream_t stream) {
  const float* text   = (const float*)d_in[0];
  const float* weight = (const float*)d_in[1];
  const float* fcw    = (const float*)d_in[2];
  const float* attn_l = (const float*)d_in[3];
  const float* attn_r = (const float*)d_in[4];
  const float* bias   = (const float*)d_in[5];
  const int*   src    = (const int*)d_in[6];
  const int*   dst    = (const int*)d_in[7];
  const int E = in_sizes[6];
  const int N = in_sizes[0] / 512;   // 16384

  char* ws = (char*)d_ws;
  size_t o = 0;
  auto carve = [&](size_t bytes) { void* p = ws + o; o = (o + bytes + 255) & ~(size_t)255; return p; };
  short* textb = (short*)carve((size_t)N * 512 * 2);   // 16.8 MB
  short* w2t   = (short*)carve((size_t)512 * 512 * 2); // 0.5 MB
  short* h     = (short*)carve((size_t)N * 512 * 2);   // 16.8 MB
  float* el    = (float*)carve((size_t)N * 4 * 4);
  float* er    = (float*)carve((size_t)N * 4 * 4);
  int*   deg   = (int*)carve((size_t)N * 4);
  int*   off   = (int*)carve(((size_t)N + 1) * 4);
  int*   cur   = (int*)carve((size_t)N * 4);
  int*   csr   = (int*)carve((size_t)E * 4);

  hipMemsetAsync(deg, 0, (size_t)N * 4, stream);
  k_w2t<<<dim3(16, 16), dim3(32, 32), 0, stream>>>(weight, fcw, w2t);
  k_f32_to_bf16<<<(N * 512 / 8 + 255) / 256, 256, 0, stream>>>(text, textb, N * 512 / 8);
  k_gemm<<<dim3(512 / BN, N / BM), 256, 0, stream>>>(textb, w2t, h, N, 512, 512);
  k_eler<<<N / 4, 256, 0, stream>>>(h, attn_l, attn_r, el, er, N);
  k_hist<<<(E + 255) / 256, 256, 0, stream>>>(dst, deg, E);
  k_scan<<<1, 1024, 0, stream>>>(deg, off, cur, N);
  k_scatter<<<(E + 255) / 256, 256, 0, stream>>>(src, dst, cur, csr, E);
  k_aggregate<<<N / 4, 256, 0, stream>>>(off, csr, el, er, h, bias, (float*)d_out, N);
}